// Round 3
// baseline (1884.633 us; speedup 1.0000x reference)
//
#include <hip/hip_runtime.h>

// Problem constants
#define B_    128
#define HIDD  512
#define NCLS  7000
#define NPAD  7040
#define LSEQ  40
#define MROWS 5120   // LSEQ * B_
#define TT    10     // t-steps per k_feat block (40 = 4 * 10)

typedef __attribute__((ext_vector_type(8))) short bf16x8;
typedef __attribute__((ext_vector_type(4))) float f32x4;

__device__ __forceinline__ unsigned short f2bf(float x) {
  union { float f; unsigned u; } v; v.f = x;
  unsigned r = v.u + 0x7fffu + ((v.u >> 16) & 1u);   // RNE
  return (unsigned short)(r >> 16);
}
__device__ __forceinline__ float bf2f(unsigned short h) {
  union { unsigned u; float f; } v; v.u = ((unsigned)h) << 16;
  return v.f;
}
__device__ __forceinline__ float sigm(float x) { return 1.f / (1.f + __expf(-x)); }
__device__ __forceinline__ float tanh_f(float x) {
  float e = __expf(2.f * x);
  return 1.f - 2.f / (e + 1.f);
}
__device__ __forceinline__ float rcp_f(float x) { return __builtin_amdgcn_rcpf(x); }

// ---------------- fp32 -> bf16 convert (vectorized x4) ----------------
__global__ __launch_bounds__(256) void k_cvt(const float* __restrict__ src,
                                             unsigned short* __restrict__ dst, int n4) {
  int i = blockIdx.x * 256 + threadIdx.x;
  if (i >= n4) return;
  float4 v = ((const float4*)src)[i];
  ushort4 o; o.x = f2bf(v.x); o.y = f2bf(v.y); o.z = f2bf(v.z); o.w = f2bf(v.w);
  ((ushort4*)dst)[i] = o;
}

// x_em fp32 -> Ex = exp(2*x) bf16 (same [b][c][p] layout)
__global__ __launch_bounds__(256) void k_expcvt(const float* __restrict__ src,
                                                unsigned short* __restrict__ dst, int n4) {
  int i = blockIdx.x * 256 + threadIdx.x;
  if (i >= n4) return;
  float4 v = ((const float4*)src)[i];
  ushort4 o;
  o.x = f2bf(__expf(2.f * v.x)); o.y = f2bf(__expf(2.f * v.y));
  o.z = f2bf(__expf(2.f * v.z)); o.w = f2bf(__expf(2.f * v.w));
  ((ushort4*)dst)[i] = o;
}

// lin_w [7000][1024] -> bf16 padded [7040][1024] (pad rows zero)
__global__ __launch_bounds__(256) void k_linpad(const float* __restrict__ lw,
                                                unsigned short* __restrict__ dst) {
  int i = blockIdx.x * 256 + threadIdx.x;   // over 7040*1024/4
  int e = i * 4;
  int row = e >> 10;
  ushort4 o;
  if (row < NCLS) {
    float4 v = *(const float4*)(lw + (size_t)row * 1024 + (e & 1023));
    o.x = f2bf(v.x); o.y = f2bf(v.y); o.z = f2bf(v.z); o.w = f2bf(v.w);
  } else { o.x = 0; o.y = 0; o.z = 0; o.w = 0; }
  ((ushort4*)dst)[i] = o;
}

// teacher-forced inputs xts[l*128+b][512], bf16. l=0: hidden_en[-1]; l>0: embed_w[target[b][l-1]]
__global__ __launch_bounds__(256) void k_xts(const float* __restrict__ hidden_en,
                                             const float* __restrict__ embed_w,
                                             const int* __restrict__ target,
                                             unsigned short* __restrict__ xts) {
  int i = blockIdx.x * 256 + threadIdx.x;   // over 5120*512/4
  int e = i * 4;
  int r = e >> 9, col = e & 511;
  int l = r >> 7, b = r & 127;
  const float* src;
  if (l == 0) src = hidden_en + b * 512 + col;
  else        src = embed_w + (size_t)target[b * LSEQ + (l - 1)] * 512 + col;
  float4 v = *(const float4*)src;
  ushort4 o; o.x = f2bf(v.x); o.y = f2bf(v.y); o.z = f2bf(v.z); o.w = f2bf(v.w);
  ((ushort4*)xts)[i] = o;
}

// W_hh fp32 [2048][512] -> Wb bf16 fragment-major: [jwb(32)][g(4)][kg(16)][lane(64)][8]
// b-frag for (block jwb, gate g, k-chunk kg): lane=quad*16+l16 holds W_hh[g*512+jwb*16+l16][kg*32+quad*8 .. +7]
__global__ __launch_bounds__(256) void k_wprep(const float* __restrict__ W_hh,
                                               unsigned short* __restrict__ Wb) {
  int idx = blockIdx.x * 256 + threadIdx.x;   // 131072
  int lane = idx & 63, kg = (idx >> 6) & 15, g = (idx >> 10) & 3, jwb = idx >> 12;
  int l16 = lane & 15, quad = lane >> 4;
  const float* src = W_hh + (size_t)(g * 512 + jwb * 16 + l16) * 512 + kg * 32 + quad * 8;
  float4 v0 = *(const float4*)src, v1 = *(const float4*)(src + 4);
  unsigned short o[8] = {f2bf(v0.x), f2bf(v0.y), f2bf(v0.z), f2bf(v0.w),
                         f2bf(v1.x), f2bf(v1.y), f2bf(v1.z), f2bf(v1.w)};
  *(ushort4*)(Wb + (size_t)idx * 8)     = *(ushort4*)o;
  *(ushort4*)(Wb + (size_t)idx * 8 + 4) = *(ushort4*)(o + 4);
}

__global__ void k_binit(unsigned* bar) { bar[0] = 0; bar[1] = 0; }

// ---------------- persistent LSTM scan: all 40 steps in one launch ----------------
// 32 blocks x 1024 threads; block jwb owns j-window [jwb*16, jwb*16+16) across all 4 gates.
// c stays in LDS all 40 steps; h round-trips via global bf16 hG with a device-scope grid barrier.
__global__ __launch_bounds__(1024) void k_scan(const unsigned short* __restrict__ xg,
                                               const unsigned short* __restrict__ Wb,
                                               const float* __restrict__ b_hh,
                                               unsigned short* __restrict__ hG,
                                               unsigned short* __restrict__ hatt,
                                               unsigned* __restrict__ bar) {
  __shared__ __align__(16) char uS[34816];        // union: hs[128][136] bf16 / gsum[4][128][17] f32
  unsigned short* hs = (unsigned short*)uS;
  float* gsum = (float*)uS;
  __shared__ float cS[2048];
  __shared__ float bhL[64];
  const int tid = threadIdx.x;
  const int lane = tid & 63, wid = tid >> 6;
  const int l16 = lane & 15, quad = lane >> 4;
  const int mt2 = wid & 3, g = wid >> 2;          // wave: m-tile pair mt2, gate g
  const int jwb = blockIdx.x, jw = jwb * 16;
  if (tid < 64) bhL[tid] = b_hh[(tid >> 4) * 512 + jw + (tid & 15)];
  __syncthreads();
  for (int t = 0; t < LSEQ; t++) {
    if (t > 0) {
      f32x4 acc0 = {0.f, 0.f, 0.f, 0.f}, acc1 = {0.f, 0.f, 0.f, 0.f};
      for (int k0 = 0; k0 < 512; k0 += 128) {
#pragma unroll
        for (int pass = 0; pass < 2; pass++) {
          int i = pass * 1024 + tid;
          int row = i >> 4, kc = (i & 15) << 3;
          *(bf16x8*)&hs[row * 136 + kc] = *(const bf16x8*)&hG[row * 512 + k0 + kc];
        }
        __syncthreads();
#pragma unroll
        for (int kk = 0; kk < 4; kk++) {
          int kg = (k0 >> 5) + kk;
          bf16x8 b  = *(const bf16x8*)&Wb[((((size_t)jwb * 4 + g) * 16 + kg) * 64 + lane) * 8];
          bf16x8 a0 = *(const bf16x8*)&hs[(mt2 * 32 + l16) * 136 + kk * 32 + quad * 8];
          bf16x8 a1 = *(const bf16x8*)&hs[(mt2 * 32 + 16 + l16) * 136 + kk * 32 + quad * 8];
          acc0 = __builtin_amdgcn_mfma_f32_16x16x32_bf16(a0, b, acc0, 0, 0, 0);
          acc1 = __builtin_amdgcn_mfma_f32_16x16x32_bf16(a1, b, acc1, 0, 0, 0);
        }
        __syncthreads();
      }
      // gate exchange (C/D layout: col=l16, row=quad*4+r)
#pragma unroll
      for (int r = 0; r < 4; r++) {
        gsum[g * 2176 + (mt2 * 32 + quad * 4 + r) * 17 + l16]      = acc0[r];
        gsum[g * 2176 + (mt2 * 32 + 16 + quad * 4 + r) * 17 + l16] = acc1[r];
      }
      __syncthreads();
    }
    // cell update: 2048 elements (m 0..127, jj 0..15), 2 per thread
#pragma unroll
    for (int half = 0; half < 2; half++) {
      int e = half * 1024 + tid;
      int m = e >> 4, jj = e & 15;
      size_t xr = ((size_t)t * 128 + m) * 2048 + jw + jj;
      float a0 = bf2f(xg[xr])        + bhL[jj];
      float a1 = bf2f(xg[xr + 512])  + bhL[16 + jj];
      float a2 = bf2f(xg[xr + 1024]) + bhL[32 + jj];
      float a3 = bf2f(xg[xr + 1536]) + bhL[48 + jj];
      float c_old = 0.f;
      if (t > 0) {
        a0 += gsum[m * 17 + jj];
        a1 += gsum[2176 + m * 17 + jj];
        a2 += gsum[2 * 2176 + m * 17 + jj];
        a3 += gsum[3 * 2176 + m * 17 + jj];
        c_old = cS[e];
      }
      float c = sigm(a1) * c_old + sigm(a0) * tanh_f(a2);
      float h = sigm(a3) * tanh_f(c);
      cS[e] = c;
      unsigned short hb = f2bf(h);
      hG[m * 512 + jw + jj] = hb;
      hatt[((size_t)t * 128 + m) * 1024 + jw + jj] = hb;
    }
    if (t < LSEQ - 1) {
      __threadfence();                 // release: flush h writes to device scope
      __syncthreads();
      if (tid == 0) {
        unsigned gen = __hip_atomic_load(&bar[1], __ATOMIC_RELAXED, __HIP_MEMORY_SCOPE_AGENT);
        unsigned a = __hip_atomic_fetch_add(&bar[0], 1u, __ATOMIC_ACQ_REL, __HIP_MEMORY_SCOPE_AGENT);
        if (a == 31u) {
          __hip_atomic_store(&bar[0], 0u, __ATOMIC_RELAXED, __HIP_MEMORY_SCOPE_AGENT);
          __hip_atomic_store(&bar[1], gen + 1u, __ATOMIC_RELEASE, __HIP_MEMORY_SCOPE_AGENT);
        } else {
          while (__hip_atomic_load(&bar[1], __ATOMIC_ACQUIRE, __HIP_MEMORY_SCOPE_AGENT) == gen)
            __builtin_amdgcn_s_sleep(2);
        }
      }
      __syncthreads();
      __threadfence();                 // acquire: invalidate L1/L2 before reading others' h
    }
  }
}

// ---------------- bf16 MFMA GEMM: C[M][N] = A[M][K] @ Bw[N][K]^T + bias ----------------
// MODE 0: out bf16 (xg). MODE 2: logits -> d_out with (t,b) swizzle + n<7000 guard.
// MODE 3: out fp32 = exp(2*(v+bias))  (Eh for attention).
template <int MODE>
__global__ __launch_bounds__(256) void k_gemm(const unsigned short* __restrict__ A, int lda,
                                              const unsigned short* __restrict__ Bw, int ldb,
                                              const float* __restrict__ bias,
                                              void* __restrict__ outp, int ldc, int K) {
  __shared__ __align__(16) unsigned short As[128 * 32];
  __shared__ __align__(16) unsigned short Bs[128 * 32];
  const int tid = threadIdx.x;
  const int lane = tid & 63, wid = tid >> 6;
  const int wm = wid >> 1, wn = wid & 1;
  const int quad = lane >> 4, l16 = lane & 15;
  const int m0 = blockIdx.x * 128, n0 = blockIdx.y * 128;
  f32x4 acc[4][4];
#pragma unroll
  for (int i = 0; i < 4; i++)
#pragma unroll
    for (int j = 0; j < 4; j++) acc[i][j] = (f32x4){0.f, 0.f, 0.f, 0.f};

  const int r0 = tid >> 2, kq0 = (tid & 3) * 8;
  for (int k0 = 0; k0 < K; k0 += 32) {
#pragma unroll
    for (int s = 0; s < 2; s++) {
      int row = r0 + s * 64;
      *(bf16x8*)(As + row * 32 + kq0) = *(const bf16x8*)(A + (size_t)(m0 + row) * lda + k0 + kq0);
      *(bf16x8*)(Bs + row * 32 + kq0) = *(const bf16x8*)(Bw + (size_t)(n0 + row) * ldb + k0 + kq0);
    }
    __syncthreads();
    bf16x8 af[4], bfr[4];
#pragma unroll
    for (int i = 0; i < 4; i++)
      af[i] = *(const bf16x8*)(As + (wm * 64 + i * 16 + l16) * 32 + quad * 8);
#pragma unroll
    for (int j = 0; j < 4; j++)
      bfr[j] = *(const bf16x8*)(Bs + (wn * 64 + j * 16 + l16) * 32 + quad * 8);
#pragma unroll
    for (int i = 0; i < 4; i++)
#pragma unroll
      for (int j = 0; j < 4; j++)
        acc[i][j] = __builtin_amdgcn_mfma_f32_16x16x32_bf16(af[i], bfr[j], acc[i][j], 0, 0, 0);
    __syncthreads();
  }
#pragma unroll
  for (int i = 0; i < 4; i++) {
    int mbase = m0 + wm * 64 + i * 16 + quad * 4;
#pragma unroll
    for (int j = 0; j < 4; j++) {
      int n = n0 + wn * 64 + j * 16 + l16;
#pragma unroll
      for (int r = 0; r < 4; r++) {
        float v = acc[i][j][r];
        int m = mbase + r;
        if (MODE == 0) {
          ((unsigned short*)outp)[(size_t)m * ldc + n] = f2bf(v + bias[n]);
        } else if (MODE == 3) {
          ((float*)outp)[(size_t)m * ldc + n] = __expf(2.f * (v + bias[n]));
        } else {
          if (n < NCLS) {
            int t = m >> 7, b = m & 127;
            ((float*)outp)[((size_t)(b * LSEQ + t)) * NCLS + n] = v + bias[n];
          }
        }
      }
    }
  }
}

// ---------------- attention scores via exp-factorized tanh ----------------
__global__ __launch_bounds__(256) void k_feat(const float* __restrict__ Eh,
                                              const unsigned short* __restrict__ Ex,
                                              const float* __restrict__ attw_w,
                                              float* __restrict__ s_all) {
  __shared__ float EhL[TT][512];
  __shared__ float wL[512];
  const int tid = threadIdx.x;
  const int tg = blockIdx.x >> 7, b = blockIdx.x & 127;
  const int t0 = tg * TT;
  for (int i = tid * 4; i < TT * 512; i += 1024) {
    int t = i >> 9, c = i & 511;
    *(float4*)&EhL[t][c] = *(const float4*)&Eh[((size_t)(t0 + t) * 128 + b) * 512 + c];
  }
  if (tid < 128) *(float4*)&wL[tid * 4] = *(const float4*)&attw_w[tid * 4];
  __syncthreads();
  const int p = tid;
  const unsigned short* xp = Ex + (size_t)b * 512 * 256 + p;
  float acc[TT];
#pragma unroll
  for (int t = 0; t < TT; t++) acc[t] = 0.f;
  for (int c0 = 0; c0 < 512; c0 += 4) {
    float ex0 = bf2f(xp[(size_t)(c0 + 0) * 256]);
    float ex1 = bf2f(xp[(size_t)(c0 + 1) * 256]);
    float ex2 = bf2f(xp[(size_t)(c0 + 2) * 256]);
    float ex3 = bf2f(xp[(size_t)(c0 + 3) * 256]);
    float4 wv = *(const float4*)&wL[c0];
#pragma unroll
    for (int t = 0; t < TT; t++) {
      float4 eh = *(const float4*)&EhL[t][c0];
      acc[t] = __builtin_fmaf(wv.x, rcp_f(__builtin_fmaf(ex0, eh.x, 1.f)), acc[t]);
      acc[t] = __builtin_fmaf(wv.y, rcp_f(__builtin_fmaf(ex1, eh.y, 1.f)), acc[t]);
      acc[t] = __builtin_fmaf(wv.z, rcp_f(__builtin_fmaf(ex2, eh.z, 1.f)), acc[t]);
      acc[t] = __builtin_fmaf(wv.w, rcp_f(__builtin_fmaf(ex3, eh.w, 1.f)), acc[t]);
    }
  }
#pragma unroll
  for (int t = 0; t < TT; t++)
    s_all[((size_t)(t0 + t) * 128 + b) * 256 + p] = -2.f * acc[t];
}

// ---------------- softmax over p (per t,b) + att[t,b,d] = sum_p alpha * att_x_em[b,p,d] ----------------
__global__ __launch_bounds__(256) void k_att(const float* __restrict__ s_all,
                                             const float* __restrict__ atx,
                                             unsigned short* __restrict__ hatt) {
  __shared__ float sL[40][257];
  __shared__ float zinv[40];
  const int tid = threadIdx.x;
  const int b = blockIdx.x >> 1, dh = blockIdx.x & 1;
  for (int i = tid; i < 40 * 256; i += 256) {
    int t = i >> 8, p = i & 255;
    sL[t][p] = s_all[((size_t)t * 128 + b) * 256 + p];
  }
  __syncthreads();
  if (tid < 40) {
    int t = tid;
    float mx = -1e30f;
    for (int p = 0; p < 256; p++) mx = fmaxf(mx, sL[t][p]);
    float z = 0.f;
    for (int p = 0; p < 256; p++) { float e = __expf(sL[t][p] - mx); sL[t][p] = e; z += e; }
    zinv[t] = 1.f / z;
  }
  __syncthreads();
  float acc[40];
#pragma unroll
  for (int t = 0; t < 40; t++) acc[t] = 0.f;
  const int d = dh * 256 + tid;
  const float* ap = atx + (size_t)b * 256 * 512 + d;
  for (int p = 0; p < 256; p++) {
    float av = ap[(size_t)p * 512];
#pragma unroll
    for (int t = 0; t < 40; t++) acc[t] += sL[t][p] * av;
  }
#pragma unroll
  for (int t = 0; t < 40; t++) {
    float v = acc[t] * zinv[t];
    hatt[((size_t)t * 128 + b) * 1024 + 512 + d] = f2bf(v);
  }
}

// ---------------- in-place log_softmax over rows of 7000 in d_out ----------------
__global__ __launch_bounds__(256) void k_lsm(float* __restrict__ out) {
  __shared__ float buf[7000];
  __shared__ float red[256];
  const int tid = threadIdx.x;
  float* pr = out + (size_t)blockIdx.x * NCLS;
  for (int i = tid * 4; i < NCLS; i += 1024)
    *(float4*)&buf[i] = *(const float4*)&pr[i];
  __syncthreads();
  float mx = -1e30f;
  for (int i = tid; i < NCLS; i += 256) mx = fmaxf(mx, buf[i]);
  red[tid] = mx; __syncthreads();
  for (int s = 128; s > 0; s >>= 1) { if (tid < s) red[tid] = fmaxf(red[tid], red[tid + s]); __syncthreads(); }
  mx = red[0]; __syncthreads();
  float sum = 0.f;
  for (int i = tid; i < NCLS; i += 256) sum += __expf(buf[i] - mx);
  red[tid] = sum; __syncthreads();
  for (int s = 128; s > 0; s >>= 1) { if (tid < s) red[tid] += red[tid + s]; __syncthreads(); }
  float lse = mx + __logf(red[0]);
  for (int i = tid * 4; i < NCLS; i += 1024) {
    float4 v = *(const float4*)&buf[i];
    v.x -= lse; v.y -= lse; v.z -= lse; v.w -= lse;
    *(float4*)&pr[i] = v;
  }
}

extern "C" void kernel_launch(void* const* d_in, const int* in_sizes, int n_in,
                              void* d_out, int out_size, void* d_ws, size_t ws_size,
                              hipStream_t stream) {
  const float* hidden_en = (const float*)d_in[0];
  const float* x_em      = (const float*)d_in[1];
  const float* att_x     = (const float*)d_in[2];
  const int*   target    = (const int*)d_in[3];
  const float* embed_w   = (const float*)d_in[6];
  const float* W_ih      = (const float*)d_in[7];
  const float* W_hh      = (const float*)d_in[8];
  const float* b_ih      = (const float*)d_in[9];
  const float* b_hh      = (const float*)d_in[10];
  const float* hem_w     = (const float*)d_in[11];
  const float* hem_b     = (const float*)d_in[12];
  const float* attw_w    = (const float*)d_in[13];
  const float* lin_w     = (const float*)d_in[15];
  const float* lin_b     = (const float*)d_in[16];
  float* out = (float*)d_out;
  (void)in_sizes; (void)n_in; (void)out_size; (void)ws_size;

  char* w = (char*)d_ws;
  size_t off = 0;
  auto alloc = [&](size_t bytes) { char* p = w + off; off = (off + bytes + 255) & ~(size_t)255; return p; };
  unsigned short* xts  = (unsigned short*)alloc((size_t)MROWS * 512 * 2);
  unsigned short* wih  = (unsigned short*)alloc((size_t)2048 * 512 * 2);
  unsigned short* xg   = (unsigned short*)alloc((size_t)MROWS * 2048 * 2);
  unsigned short* hemw = (unsigned short*)alloc((size_t)512 * 512 * 2);
  unsigned short* linw = (unsigned short*)alloc((size_t)NPAD * 1024 * 2);
  unsigned short* xem  = (unsigned short*)alloc((size_t)128 * 512 * 256 * 2);  // Ex = exp(2*x_em) bf16
  unsigned short* hatt = (unsigned short*)alloc((size_t)MROWS * 1024 * 2);
  unsigned short* wb   = (unsigned short*)alloc((size_t)2048 * 512 * 2);       // W_hh bf16 fragment-major
  unsigned short* hG   = (unsigned short*)alloc((size_t)128 * 512 * 2);        // h between scan steps
  unsigned*       bar  = (unsigned*)alloc(256);
  float* eh_all  = (float*)alloc((size_t)MROWS * 512 * 4);   // Eh = exp(2*hem)
  float* s_all   = (float*)alloc((size_t)MROWS * 256 * 4);

  // --- precompute / conversions ---
  k_cvt<<<1024, 256, 0, stream>>>(W_ih, wih, 2048 * 512 / 4);
  k_cvt<<<256, 256, 0, stream>>>(hem_w, hemw, 512 * 512 / 4);
  k_expcvt<<<16384, 256, 0, stream>>>(x_em, xem, 128 * 512 * 256 / 4);
  k_linpad<<<NPAD * 1024 / 4 / 256, 256, 0, stream>>>(lin_w, linw);
  k_xts<<<MROWS * 512 / 4 / 256, 256, 0, stream>>>(hidden_en, embed_w, target, xts);
  k_wprep<<<512, 256, 0, stream>>>(W_hh, wb);
  k_binit<<<1, 1, 0, stream>>>(bar);
  // xg_all = xts @ W_ih^T + b_ih  (bf16 out)
  k_gemm<0><<<dim3(40, 16), 256, 0, stream>>>(xts, 512, wih, 512, b_ih, xg, 2048, 512);

  // --- persistent sequential LSTM scan (one launch, grid barrier between steps) ---
  k_scan<<<32, 1024, 0, stream>>>(xg, wb, b_hh, hG, hatt, bar);

  // --- batched attention over all 40 steps ---
  k_gemm<3><<<dim3(40, 4), 256, 0, stream>>>(hatt, 1024, hemw, 512, hem_b, eh_all, 512, 512);
  k_feat<<<512, 256, 0, stream>>>(eh_all, xem, attw_w, s_all);
  k_att<<<256, 256, 0, stream>>>(s_all, att_x, hatt);

  // --- logits + log_softmax ---
  k_gemm<2><<<dim3(40, 55), 256, 0, stream>>>(hatt, 1024, linw, 1024, lin_b, out, NCLS, 1024);
  k_lsm<<<MROWS, 256, 0, stream>>>(out);
}

// Round 4
// 1456.896 us; speedup vs baseline: 1.2936x; 1.2936x over previous
//
#include <hip/hip_runtime.h>

// Problem constants
#define B_    128
#define HIDD  512
#define NCLS  7000
#define NPAD  7040
#define LSEQ  40
#define MROWS 5120   // LSEQ * B_
#define TT    10     // t-steps per k_feat block (40 = 4 * 10)

typedef __attribute__((ext_vector_type(8))) short bf16x8;
typedef __attribute__((ext_vector_type(4))) float f32x4;

__device__ __forceinline__ unsigned short f2bf(float x) {
  union { float f; unsigned u; } v; v.f = x;
  unsigned r = v.u + 0x7fffu + ((v.u >> 16) & 1u);   // RNE
  return (unsigned short)(r >> 16);
}
__device__ __forceinline__ float bf2f(unsigned short h) {
  union { unsigned u; float f; } v; v.u = ((unsigned)h) << 16;
  return v.f;
}
__device__ __forceinline__ float sigm(float x) { return 1.f / (1.f + __expf(-x)); }
__device__ __forceinline__ float tanh_f(float x) {
  float e = __expf(2.f * x);
  return 1.f - 2.f / (e + 1.f);
}
__device__ __forceinline__ float rcp_f(float x) { return __builtin_amdgcn_rcpf(x); }

// ---------------- fp32 -> bf16 convert (vectorized x4) ----------------
__global__ __launch_bounds__(256) void k_cvt(const float* __restrict__ src,
                                             unsigned short* __restrict__ dst, int n4) {
  int i = blockIdx.x * 256 + threadIdx.x;
  if (i >= n4) return;
  float4 v = ((const float4*)src)[i];
  ushort4 o; o.x = f2bf(v.x); o.y = f2bf(v.y); o.z = f2bf(v.z); o.w = f2bf(v.w);
  ((ushort4*)dst)[i] = o;
}

// zero a float4 region
__global__ __launch_bounds__(256) void k_zero(float4* __restrict__ dst, int n4) {
  int i = blockIdx.x * 256 + threadIdx.x;
  if (i < n4) dst[i] = (float4){0.f, 0.f, 0.f, 0.f};
}

// x_em fp32 -> Ex = exp(2*x) bf16 (same [b][c][p] layout)
__global__ __launch_bounds__(256) void k_expcvt(const float* __restrict__ src,
                                                unsigned short* __restrict__ dst, int n4) {
  int i = blockIdx.x * 256 + threadIdx.x;
  if (i >= n4) return;
  float4 v = ((const float4*)src)[i];
  ushort4 o;
  o.x = f2bf(__expf(2.f * v.x)); o.y = f2bf(__expf(2.f * v.y));
  o.z = f2bf(__expf(2.f * v.z)); o.w = f2bf(__expf(2.f * v.w));
  ((ushort4*)dst)[i] = o;
}

// lin_w [7000][1024] -> bf16 padded [7040][1024] (pad rows zero)
__global__ __launch_bounds__(256) void k_linpad(const float* __restrict__ lw,
                                                unsigned short* __restrict__ dst) {
  int i = blockIdx.x * 256 + threadIdx.x;   // over 7040*1024/4
  int e = i * 4;
  int row = e >> 10;
  ushort4 o;
  if (row < NCLS) {
    float4 v = *(const float4*)(lw + (size_t)row * 1024 + (e & 1023));
    o.x = f2bf(v.x); o.y = f2bf(v.y); o.z = f2bf(v.z); o.w = f2bf(v.w);
  } else { o.x = 0; o.y = 0; o.z = 0; o.w = 0; }
  ((ushort4*)dst)[i] = o;
}

// teacher-forced inputs xts[l*128+b][512], bf16. l=0: hidden_en[-1]; l>0: embed_w[target[b][l-1]]
__global__ __launch_bounds__(256) void k_xts(const float* __restrict__ hidden_en,
                                             const float* __restrict__ embed_w,
                                             const int* __restrict__ target,
                                             unsigned short* __restrict__ xts) {
  int i = blockIdx.x * 256 + threadIdx.x;   // over 5120*512/4
  int e = i * 4;
  int r = e >> 9, col = e & 511;
  int l = r >> 7, b = r & 127;
  const float* src;
  if (l == 0) src = hidden_en + b * 512 + col;
  else        src = embed_w + (size_t)target[b * LSEQ + (l - 1)] * 512 + col;
  float4 v = *(const float4*)src;
  ushort4 o; o.x = f2bf(v.x); o.y = f2bf(v.y); o.z = f2bf(v.z); o.w = f2bf(v.w);
  ((ushort4*)xts)[i] = o;
}

// W_hh fp32 [2048][512] -> Wp bf16 permuted rows: Wp[jb*128 + g*32 + jj] = W_hh[g*512 + jb*32 + jj]
// so block jb's 128-row N-tile holds all 4 gates of j-window [jb*32, jb*32+32)
__global__ __launch_bounds__(256) void k_wprep(const float* __restrict__ W_hh,
                                               unsigned short* __restrict__ Wp) {
  int i = blockIdx.x * 256 + threadIdx.x;   // over 2048*512/4 = 262144
  int e = i * 4;
  int rp = e >> 9, k = e & 511;
  int jb = rp >> 7, rr = rp & 127, g = rr >> 5, jj = rr & 31;
  const float* src = W_hh + (size_t)(g * 512 + jb * 32 + jj) * 512 + k;
  float4 v = *(const float4*)src;
  ushort4 o; o.x = f2bf(v.x); o.y = f2bf(v.y); o.z = f2bf(v.z); o.w = f2bf(v.w);
  ((ushort4*)Wp)[i] = o;
}

// ---------------- one LSTM time step: 16 blocks, each owns a 32-wide j-window ----------------
// gates(128 m x 128 r') = h_prev @ Wp_slice^T via MFMA; epilogue does the cell update block-locally.
__global__ __launch_bounds__(256) void k_step(const unsigned short* __restrict__ hin,
                                              unsigned short* __restrict__ hout,
                                              const unsigned short* __restrict__ Wp,
                                              const unsigned short* __restrict__ xg,
                                              const float* __restrict__ b_hh,
                                              float* __restrict__ cG,
                                              unsigned short* __restrict__ hatt, int t) {
  __shared__ __align__(16) char uS[34816];   // union: As(8K)+Bs(8K) staging | gbuf[64][136] f32
  unsigned short* As = (unsigned short*)uS;
  unsigned short* Bs = (unsigned short*)(uS + 8192);
  float* gbuf = (float*)uS;
  __shared__ float biasL[128];
  const int tid = threadIdx.x;
  const int lane = tid & 63, wid = tid >> 6;
  const int wm = wid >> 1, wn = wid & 1;
  const int quad = lane >> 4, l16 = lane & 15;
  const int jb = blockIdx.x, jw = jb * 32;
  if (tid < 128) biasL[tid] = b_hh[(tid >> 5) * 512 + jw + (tid & 31)];

  f32x4 acc[4][4];
#pragma unroll
  for (int i = 0; i < 4; i++)
#pragma unroll
    for (int j = 0; j < 4; j++) acc[i][j] = (f32x4){0.f, 0.f, 0.f, 0.f};

  const unsigned short* Bw = Wp + (size_t)jb * 128 * 512;
  const int r0 = tid >> 2, kq0 = (tid & 3) * 8;
  for (int k0 = 0; k0 < 512; k0 += 32) {
#pragma unroll
    for (int s = 0; s < 2; s++) {
      int row = r0 + s * 64;
      *(bf16x8*)(As + row * 32 + kq0) = *(const bf16x8*)(hin + (size_t)row * 512 + k0 + kq0);
      *(bf16x8*)(Bs + row * 32 + kq0) = *(const bf16x8*)(Bw + (size_t)row * 512 + k0 + kq0);
    }
    __syncthreads();
    bf16x8 af[4], bfr[4];
#pragma unroll
    for (int i = 0; i < 4; i++)
      af[i] = *(const bf16x8*)(As + (wm * 64 + i * 16 + l16) * 32 + quad * 8);
#pragma unroll
    for (int j = 0; j < 4; j++)
      bfr[j] = *(const bf16x8*)(Bs + (wn * 64 + j * 16 + l16) * 32 + quad * 8);
#pragma unroll
    for (int i = 0; i < 4; i++)
#pragma unroll
      for (int j = 0; j < 4; j++)
        acc[i][j] = __builtin_amdgcn_mfma_f32_16x16x32_bf16(af[i], bfr[j], acc[i][j], 0, 0, 0);
    __syncthreads();
  }
  // epilogue in two m-half passes through gbuf (m-local 64 x n 128, pad 136)
#pragma unroll
  for (int half = 0; half < 2; half++) {
    if (wm == half) {
#pragma unroll
      for (int i = 0; i < 4; i++)
#pragma unroll
        for (int j = 0; j < 4; j++)
#pragma unroll
          for (int r = 0; r < 4; r++)
            gbuf[(i * 16 + quad * 4 + r) * 136 + wn * 64 + j * 16 + l16] = acc[i][j][r];
    }
    __syncthreads();
    // cell update for m in [half*64, half*64+64): 2048 elems, 8 per thread
    for (int e = tid; e < 2048; e += 256) {
      int ml = e >> 5, jj = e & 31;
      int m = half * 64 + ml;
      size_t xr = ((size_t)t * 128 + m) * 2048 + jw + jj;
      float a0 = gbuf[ml * 136 + jj]      + bf2f(xg[xr])        + biasL[jj];
      float a1 = gbuf[ml * 136 + 32 + jj] + bf2f(xg[xr + 512])  + biasL[32 + jj];
      float a2 = gbuf[ml * 136 + 64 + jj] + bf2f(xg[xr + 1024]) + biasL[64 + jj];
      float a3 = gbuf[ml * 136 + 96 + jj] + bf2f(xg[xr + 1536]) + biasL[96 + jj];
      size_t ci = (size_t)(jb * 128 + m) * 32 + jj;
      float c = sigm(a1) * cG[ci] + sigm(a0) * tanh_f(a2);
      float h = sigm(a3) * tanh_f(c);
      cG[ci] = c;
      unsigned short hb = f2bf(h);
      hout[(size_t)m * 512 + jw + jj] = hb;
      hatt[((size_t)t * 128 + m) * 1024 + jw + jj] = hb;
    }
    __syncthreads();
  }
}

// ---------------- bf16 MFMA GEMM: C[M][N] = A[M][K] @ Bw[N][K]^T + bias ----------------
// MODE 0: out bf16 (xg). MODE 2: logits -> d_out with (t,b) swizzle + n<7000 guard.
// MODE 3: out fp32 = exp(2*(v+bias))  (Eh for attention).
template <int MODE>
__global__ __launch_bounds__(256) void k_gemm(const unsigned short* __restrict__ A, int lda,
                                              const unsigned short* __restrict__ Bw, int ldb,
                                              const float* __restrict__ bias,
                                              void* __restrict__ outp, int ldc, int K) {
  __shared__ __align__(16) unsigned short As[128 * 32];
  __shared__ __align__(16) unsigned short Bs[128 * 32];
  const int tid = threadIdx.x;
  const int lane = tid & 63, wid = tid >> 6;
  const int wm = wid >> 1, wn = wid & 1;
  const int quad = lane >> 4, l16 = lane & 15;
  const int m0 = blockIdx.x * 128, n0 = blockIdx.y * 128;
  f32x4 acc[4][4];
#pragma unroll
  for (int i = 0; i < 4; i++)
#pragma unroll
    for (int j = 0; j < 4; j++) acc[i][j] = (f32x4){0.f, 0.f, 0.f, 0.f};

  const int r0 = tid >> 2, kq0 = (tid & 3) * 8;
  for (int k0 = 0; k0 < K; k0 += 32) {
#pragma unroll
    for (int s = 0; s < 2; s++) {
      int row = r0 + s * 64;
      *(bf16x8*)(As + row * 32 + kq0) = *(const bf16x8*)(A + (size_t)(m0 + row) * lda + k0 + kq0);
      *(bf16x8*)(Bs + row * 32 + kq0) = *(const bf16x8*)(Bw + (size_t)(n0 + row) * ldb + k0 + kq0);
    }
    __syncthreads();
    bf16x8 af[4], bfr[4];
#pragma unroll
    for (int i = 0; i < 4; i++)
      af[i] = *(const bf16x8*)(As + (wm * 64 + i * 16 + l16) * 32 + quad * 8);
#pragma unroll
    for (int j = 0; j < 4; j++)
      bfr[j] = *(const bf16x8*)(Bs + (wn * 64 + j * 16 + l16) * 32 + quad * 8);
#pragma unroll
    for (int i = 0; i < 4; i++)
#pragma unroll
      for (int j = 0; j < 4; j++)
        acc[i][j] = __builtin_amdgcn_mfma_f32_16x16x32_bf16(af[i], bfr[j], acc[i][j], 0, 0, 0);
    __syncthreads();
  }
#pragma unroll
  for (int i = 0; i < 4; i++) {
    int mbase = m0 + wm * 64 + i * 16 + quad * 4;
#pragma unroll
    for (int j = 0; j < 4; j++) {
      int n = n0 + wn * 64 + j * 16 + l16;
#pragma unroll
      for (int r = 0; r < 4; r++) {
        float v = acc[i][j][r];
        int m = mbase + r;
        if (MODE == 0) {
          ((unsigned short*)outp)[(size_t)m * ldc + n] = f2bf(v + bias[n]);
        } else if (MODE == 3) {
          ((float*)outp)[(size_t)m * ldc + n] = __expf(2.f * (v + bias[n]));
        } else {
          if (n < NCLS) {
            int t = m >> 7, b = m & 127;
            ((float*)outp)[((size_t)(b * LSEQ + t)) * NCLS + n] = v + bias[n];
          }
        }
      }
    }
  }
}

// ---------------- attention scores via exp-factorized tanh ----------------
__global__ __launch_bounds__(256) void k_feat(const float* __restrict__ Eh,
                                              const unsigned short* __restrict__ Ex,
                                              const float* __restrict__ attw_w,
                                              float* __restrict__ s_all) {
  __shared__ float EhL[TT][512];
  __shared__ float wL[512];
  const int tid = threadIdx.x;
  const int tg = blockIdx.x >> 7, b = blockIdx.x & 127;
  const int t0 = tg * TT;
  for (int i = tid * 4; i < TT * 512; i += 1024) {
    int t = i >> 9, c = i & 511;
    *(float4*)&EhL[t][c] = *(const float4*)&Eh[((size_t)(t0 + t) * 128 + b) * 512 + c];
  }
  if (tid < 128) *(float4*)&wL[tid * 4] = *(const float4*)&attw_w[tid * 4];
  __syncthreads();
  const int p = tid;
  const unsigned short* xp = Ex + (size_t)b * 512 * 256 + p;
  float acc[TT];
#pragma unroll
  for (int t = 0; t < TT; t++) acc[t] = 0.f;
  for (int c0 = 0; c0 < 512; c0 += 4) {
    float ex0 = bf2f(xp[(size_t)(c0 + 0) * 256]);
    float ex1 = bf2f(xp[(size_t)(c0 + 1) * 256]);
    float ex2 = bf2f(xp[(size_t)(c0 + 2) * 256]);
    float ex3 = bf2f(xp[(size_t)(c0 + 3) * 256]);
    float4 wv = *(const float4*)&wL[c0];
#pragma unroll
    for (int t = 0; t < TT; t++) {
      float4 eh = *(const float4*)&EhL[t][c0];
      acc[t] = __builtin_fmaf(wv.x, rcp_f(__builtin_fmaf(ex0, eh.x, 1.f)), acc[t]);
      acc[t] = __builtin_fmaf(wv.y, rcp_f(__builtin_fmaf(ex1, eh.y, 1.f)), acc[t]);
      acc[t] = __builtin_fmaf(wv.z, rcp_f(__builtin_fmaf(ex2, eh.z, 1.f)), acc[t]);
      acc[t] = __builtin_fmaf(wv.w, rcp_f(__builtin_fmaf(ex3, eh.w, 1.f)), acc[t]);
    }
  }
#pragma unroll
  for (int t = 0; t < TT; t++)
    s_all[((size_t)(t0 + t) * 128 + b) * 256 + p] = -2.f * acc[t];
}

// ---------------- softmax over p (per t,b) + att[t,b,d] = sum_p alpha * att_x_em[b,p,d] ----------------
__global__ __launch_bounds__(256) void k_att(const float* __restrict__ s_all,
                                             const float* __restrict__ atx,
                                             unsigned short* __restrict__ hatt) {
  __shared__ float sL[40][257];
  __shared__ float zinv[40];
  const int tid = threadIdx.x;
  const int b = blockIdx.x >> 1, dh = blockIdx.x & 1;
  for (int i = tid; i < 40 * 256; i += 256) {
    int t = i >> 8, p = i & 255;
    sL[t][p] = s_all[((size_t)t * 128 + b) * 256 + p];
  }
  __syncthreads();
  if (tid < 40) {
    int t = tid;
    float mx = -1e30f;
    for (int p = 0; p < 256; p++) mx = fmaxf(mx, sL[t][p]);
    float z = 0.f;
    for (int p = 0; p < 256; p++) { float e = __expf(sL[t][p] - mx); sL[t][p] = e; z += e; }
    zinv[t] = 1.f / z;
  }
  __syncthreads();
  float acc[40];
#pragma unroll
  for (int t = 0; t < 40; t++) acc[t] = 0.f;
  const int d = dh * 256 + tid;
  const float* ap = atx + (size_t)b * 256 * 512 + d;
  for (int p = 0; p < 256; p++) {
    float av = ap[(size_t)p * 512];
#pragma unroll
    for (int t = 0; t < 40; t++) acc[t] += sL[t][p] * av;
  }
#pragma unroll
  for (int t = 0; t < 40; t++) {
    float v = acc[t] * zinv[t];
    hatt[((size_t)t * 128 + b) * 1024 + 512 + d] = f2bf(v);
  }
}

// ---------------- in-place log_softmax over rows of 7000 in d_out ----------------
__global__ __launch_bounds__(256) void k_lsm(float* __restrict__ out) {
  __shared__ float buf[7000];
  __shared__ float red[256];
  const int tid = threadIdx.x;
  float* pr = out + (size_t)blockIdx.x * NCLS;
  for (int i = tid * 4; i < NCLS; i += 1024)
    *(float4*)&buf[i] = *(const float4*)&pr[i];
  __syncthreads();
  float mx = -1e30f;
  for (int i = tid; i < NCLS; i += 256) mx = fmaxf(mx, buf[i]);
  red[tid] = mx; __syncthreads();
  for (int s = 128; s > 0; s >>= 1) { if (tid < s) red[tid] = fmaxf(red[tid], red[tid + s]); __syncthreads(); }
  mx = red[0]; __syncthreads();
  float sum = 0.f;
  for (int i = tid; i < NCLS; i += 256) sum += __expf(buf[i] - mx);
  red[tid] = sum; __syncthreads();
  for (int s = 128; s > 0; s >>= 1) { if (tid < s) red[tid] += red[tid + s]; __syncthreads(); }
  float lse = mx + __logf(red[0]);
  for (int i = tid * 4; i < NCLS; i += 1024) {
    float4 v = *(const float4*)&buf[i];
    v.x -= lse; v.y -= lse; v.z -= lse; v.w -= lse;
    *(float4*)&pr[i] = v;
  }
}

extern "C" void kernel_launch(void* const* d_in, const int* in_sizes, int n_in,
                              void* d_out, int out_size, void* d_ws, size_t ws_size,
                              hipStream_t stream) {
  const float* hidden_en = (const float*)d_in[0];
  const float* x_em      = (const float*)d_in[1];
  const float* att_x     = (const float*)d_in[2];
  const int*   target    = (const int*)d_in[3];
  const float* embed_w   = (const float*)d_in[6];
  const float* W_ih      = (const float*)d_in[7];
  const float* W_hh      = (const float*)d_in[8];
  const float* b_ih      = (const float*)d_in[9];
  const float* b_hh      = (const float*)d_in[10];
  const float* hem_w     = (const float*)d_in[11];
  const float* hem_b     = (const float*)d_in[12];
  const float* attw_w    = (const float*)d_in[13];
  const float* lin_w     = (const float*)d_in[15];
  const float* lin_b     = (const float*)d_in[16];
  float* out = (float*)d_out;
  (void)in_sizes; (void)n_in; (void)out_size; (void)ws_size;

  char* w = (char*)d_ws;
  size_t off = 0;
  auto alloc = [&](size_t bytes) { char* p = w + off; off = (off + bytes + 255) & ~(size_t)255; return p; };
  unsigned short* xts  = (unsigned short*)alloc((size_t)MROWS * 512 * 2);
  unsigned short* wih  = (unsigned short*)alloc((size_t)2048 * 512 * 2);
  unsigned short* xg   = (unsigned short*)alloc((size_t)MROWS * 2048 * 2);
  unsigned short* hemw = (unsigned short*)alloc((size_t)512 * 512 * 2);
  unsigned short* linw = (unsigned short*)alloc((size_t)NPAD * 1024 * 2);
  unsigned short* xem  = (unsigned short*)alloc((size_t)128 * 512 * 256 * 2);  // Ex = exp(2*x_em) bf16
  unsigned short* hatt = (unsigned short*)alloc((size_t)MROWS * 1024 * 2);
  unsigned short* wp   = (unsigned short*)alloc((size_t)2048 * 512 * 2);       // W_hh bf16, gate-interleaved rows
  // contiguous zero-init region: hG0 (128x512 bf16) + cG (16*128*32 f32)
  char* zreg = alloc(131072 + 262144);
  unsigned short* hG0 = (unsigned short*)zreg;
  float*          cG  = (float*)(zreg + 131072);
  unsigned short* hG1 = (unsigned short*)alloc((size_t)128 * 512 * 2);
  float* eh_all  = (float*)alloc((size_t)MROWS * 512 * 4);   // Eh = exp(2*hem)
  float* s_all   = (float*)alloc((size_t)MROWS * 256 * 4);

  // --- precompute / conversions ---
  k_cvt<<<1024, 256, 0, stream>>>(W_ih, wih, 2048 * 512 / 4);
  k_cvt<<<256, 256, 0, stream>>>(hem_w, hemw, 512 * 512 / 4);
  k_expcvt<<<16384, 256, 0, stream>>>(x_em, xem, 128 * 512 * 256 / 4);
  k_linpad<<<NPAD * 1024 / 4 / 256, 256, 0, stream>>>(lin_w, linw);
  k_xts<<<MROWS * 512 / 4 / 256, 256, 0, stream>>>(hidden_en, embed_w, target, xts);
  k_wprep<<<1024, 256, 0, stream>>>(W_hh, wp);
  k_zero<<<96, 256, 0, stream>>>((float4*)zreg, (131072 + 262144) / 16);
  // xg_all = xts @ W_ih^T + b_ih  (bf16 out)
  k_gemm<0><<<dim3(40, 16), 256, 0, stream>>>(xts, 512, wih, 512, b_ih, xg, 2048, 512);

  // --- sequential LSTM scan: one light MFMA kernel per step, h ping-pong ---
  for (int t = 0; t < LSEQ; t++) {
    const unsigned short* hin = (t & 1) ? hG1 : hG0;
    unsigned short* hout      = (t & 1) ? hG0 : hG1;
    k_step<<<16, 256, 0, stream>>>(hin, hout, wp, xg, b_hh, cG, hatt, t);
  }

  // --- batched attention over all 40 steps ---
  k_gemm<3><<<dim3(40, 4), 256, 0, stream>>>(hatt, 1024, hemw, 512, hem_b, eh_all, 512, 512);
  k_feat<<<512, 256, 0, stream>>>(eh_all, xem, attw_w, s_all);
  k_att<<<256, 256, 0, stream>>>(s_all, att_x, hatt);

  // --- logits + log_softmax ---
  k_gemm<2><<<dim3(40, 55), 256, 0, stream>>>(hatt, 1024, linw, 1024, lin_b, out, NCLS, 1024);
  k_lsm<<<MROWS, 256, 0, stream>>>(out);
}